// Round 11
// baseline (1606.778 us; speedup 1.0000x reference)
//
#include <hip/hip_runtime.h>
#include <hip/hip_bf16.h>

#define N_NODES 100000
#define N_EDGES 1600000
#define F_IN    128
#define H       256
#define NHID    512
#define NOUT    256
#define G_GR    256
#define NBUCK   196           // ceil(N_NODES / 512)

typedef unsigned short u16;
typedef __attribute__((ext_vector_type(8))) short s16x8;
typedef __attribute__((ext_vector_type(8))) unsigned short u16x8;
typedef __attribute__((ext_vector_type(4))) float f32x4;

__device__ __forceinline__ float bf2f(u16 u) {
    union { unsigned int i; float f; } v; v.i = ((unsigned int)u) << 16; return v.f;
}
__device__ __forceinline__ u16 f2bf(float f) {
    union { float f; unsigned int i; } v; v.f = f;
    unsigned int x = v.i;
    x += 0x7fffu + ((x >> 16) & 1u);
    return (u16)(x >> 16);
}

// ---------------- head: count_deg (atomics) fused with streaming converts ----------------
#define CD_BLKS   1563
#define SPX_BLKS  ((N_NODES * F_IN) / 1024)
#define T1_BLKS   ((F_IN * H) / 256)
#define T2_BLKS   ((H * H) / 256)
#define T3_BLKS   ((H * H) / 256)
#define TM1_BLKS  ((H * NHID) / 256)
#define TM2_BLKS  ((NHID * NOUT) / 256)
#define HEAD_BLKS (CD_BLKS + SPX_BLKS + T1_BLKS + T2_BLKS + T3_BLKS + TM1_BLKS + TM2_BLKS + 2)

__device__ __forceinline__ void transpose_split_body(const float* __restrict__ W,
        u16* __restrict__ thi, u16* __restrict__ tlo, int K, int N, int id) {
    int n = id / K, k = id - n * K;
    float f = W[(size_t)k * N + n];
    u16 h = f2bf(f);
    thi[id] = h;
    tlo[id] = f2bf(f - bf2f(h));
}

__global__ __launch_bounds__(256) void prep_head(
        const int* __restrict__ dst, int* __restrict__ degc,
        const float* __restrict__ x, u16* __restrict__ x_bf,
        const float* __restrict__ W1, u16* __restrict__ t1h, u16* __restrict__ t1l,
        const float* __restrict__ W2, u16* __restrict__ t2h, u16* __restrict__ t2l,
        const float* __restrict__ W3, u16* __restrict__ t3h, u16* __restrict__ t3l,
        const float* __restrict__ Wm1, u16* __restrict__ tm1h, u16* __restrict__ tm1l,
        const float* __restrict__ Wm2, u16* __restrict__ tm2h, u16* __restrict__ tm2l,
        const int* __restrict__ batch, int* __restrict__ goff) {
    int bid = blockIdx.x;
    if (bid < CD_BLKS) {
        int base = bid * 1024 + threadIdx.x;
#pragma unroll
        for (int q = 0; q < 4; q++) {
            int e = base + q * 256;
            if (e < N_EDGES) atomicAdd(&degc[dst[e]], 1);
        }
        return;
    }
    bid -= CD_BLKS;
    if (bid < SPX_BLKS) {
        int idx = bid * 256 + threadIdx.x;
        float4 f = *(const float4*)&x[(size_t)idx * 4];
        ushort4 o;
        o.x = f2bf(f.x); o.y = f2bf(f.y); o.z = f2bf(f.z); o.w = f2bf(f.w);
        *(ushort4*)&x_bf[(size_t)idx * 4] = o;
        return;
    }
    bid -= SPX_BLKS;
    if (bid < T1_BLKS) {
        transpose_split_body(W1, t1h, t1l, F_IN, H, bid * 256 + threadIdx.x);
        return;
    }
    bid -= T1_BLKS;
    if (bid < T2_BLKS) {
        transpose_split_body(W2, t2h, t2l, H, H, bid * 256 + threadIdx.x);
        return;
    }
    bid -= T2_BLKS;
    if (bid < T3_BLKS) {
        transpose_split_body(W3, t3h, t3l, H, H, bid * 256 + threadIdx.x);
        return;
    }
    bid -= T3_BLKS;
    if (bid < TM1_BLKS) {
        transpose_split_body(Wm1, tm1h, tm1l, H, NHID, bid * 256 + threadIdx.x);
        return;
    }
    bid -= TM1_BLKS;
    if (bid < TM2_BLKS) {
        transpose_split_body(Wm2, tm2h, tm2l, NHID, NOUT, bid * 256 + threadIdx.x);
        return;
    }
    bid -= TM2_BLKS;
    {
        int g = bid * 256 + threadIdx.x;
        if (g > G_GR) return;
        int lo = 0, hi = N_NODES;
        while (lo < hi) {
            int mid = (lo + hi) >> 1;
            if (batch[mid] < g) lo = mid + 1; else hi = mid;
        }
        goff[g] = lo;
    }
}

// ---------------- scan (CSR rowp) ----------------
__global__ void scan_partial(const int* __restrict__ cnt, int* __restrict__ partial) {
    __shared__ int s[256];
    int t = threadIdx.x;
    int i = blockIdx.x * 256 + t;
    int v = (i < N_NODES) ? cnt[i] : 0;
    s[t] = v; __syncthreads();
    for (int off = 128; off > 0; off >>= 1) {
        if (t < off) s[t] += s[t + off];
        __syncthreads();
    }
    if (t == 0) partial[blockIdx.x] = s[0];
}

__global__ void scan_offsets(int* __restrict__ partial, int nb, int* __restrict__ rowp) {
    __shared__ int s[512];
    int t = threadIdx.x;
    int orig = (t < nb) ? partial[t] : 0;
    s[t] = orig; __syncthreads();
    for (int off = 1; off < 512; off <<= 1) {
        int u = (t >= off) ? s[t - off] : 0;
        __syncthreads();
        s[t] += u;
        __syncthreads();
    }
    if (t < nb) partial[t] = s[t] - orig;
    if (t == 0) rowp[N_NODES] = N_EDGES;
}

// scan_final + node cursors + bucket cursors + dinv
__global__ void scan_final_dinv(const int* __restrict__ cnt, const int* __restrict__ partial,
                                int* __restrict__ rowp, int* __restrict__ cur,
                                int* __restrict__ bcur, float* __restrict__ dinv) {
    __shared__ int s[256];
    int t = threadIdx.x;
    int i = blockIdx.x * 256 + t;
    int v = (i < N_NODES) ? cnt[i] : 0;
    s[t] = v; __syncthreads();
    for (int off = 1; off < 256; off <<= 1) {
        int u = (t >= off) ? s[t - off] : 0;
        __syncthreads();
        s[t] += u;
        __syncthreads();
    }
    if (i < N_NODES) {
        int r = partial[blockIdx.x] + s[t] - v;
        rowp[i] = r;
        cur[i] = r;
        if ((i & 511) == 0) bcur[i >> 9] = r;   // bucket region start
        dinv[i] = rsqrtf(1.0f + (float)v);
    }
}

// ---------------- scatter phase A: bucket-level (sequential write streams, no line thrash) ----
// stage {src, w} into the bucket's CSR region; local dst (0..511) in side array.
__global__ __launch_bounds__(256) void scatter_bucket(
        const int* __restrict__ src, const int* __restrict__ dst,
        const float* __restrict__ dinv, int* __restrict__ bcur,
        int2* __restrict__ ep_stage, u16* __restrict__ dloc) {
    int base = blockIdx.x * 1024 + threadIdx.x;
#pragma unroll
    for (int q = 0; q < 4; q++) {
        int e = base + q * 256;
        if (e < N_EDGES) {
            int d = dst[e];
            int s = src[e];
            float w = dinv[d] * dinv[s];
            int b = d >> 9;
            int pos = atomicAdd(&bcur[b], 1);
            int2 v; v.x = s; v.y = __float_as_int(w);
            ep_stage[pos] = v;
            dloc[pos] = (u16)(d & 511);
        }
    }
}

// ---------------- scatter phase B: within-bucket redistribute (L2-hot window) ----------------
// 4 blocks per bucket; reads contiguous, writes random within ~50KB region.
__global__ __launch_bounds__(256) void scatter_final(
        const int* __restrict__ rowp, int* __restrict__ cur,
        const int2* __restrict__ ep_stage, const u16* __restrict__ dloc,
        int2* __restrict__ ep) {
    int b = blockIdx.x >> 2;
    int quarter = blockIdx.x & 3;
    int nodeBase = b << 9;
    int beg = rowp[nodeBase];
    int endn = nodeBase + 512; if (endn > N_NODES) endn = N_NODES;
    int end = rowp[endn];
    for (int p = beg + quarter * 256 + threadIdx.x; p < end; p += 1024) {
        int2 v = ep_stage[p];
        int d = nodeBase + dloc[p];
        int q = atomicAdd(&cur[d], 1);
        ep[q] = v;
    }
}

// ---------------- aggregation: half-wave (32 lanes x ushort8) per node, H=256 ----------------
__global__ __launch_bounds__(256) void gcn_agg256(
        const u16* __restrict__ in, const int* __restrict__ rowp,
        const int2* __restrict__ ep, const float* __restrict__ dinv,
        u16* __restrict__ outp) {
    int node = blockIdx.x * 8 + (threadIdx.x >> 5);
    int l = threadIdx.x & 31;
    int beg = rowp[node], end = rowp[node + 1];
    float a[8] = {};
    int e = beg;
    int2 pr[8];
    bool have = (e + 8 <= end);
    if (have) {
#pragma unroll
        for (int q = 0; q < 8; q++) pr[q] = ep[e + q];
    }
    while (have) {
        int2 g8[8];
#pragma unroll
        for (int q = 0; q < 8; q++) g8[q] = pr[q];
        int en = e + 8;
        bool haven = (en + 8 <= end);
        if (haven) {
#pragma unroll
            for (int q = 0; q < 8; q++) pr[q] = ep[en + q];
        }
#pragma unroll
        for (int q = 0; q < 8; q++) {
            u16x8 u = *(const u16x8*)&in[(size_t)g8[q].x * H + l * 8];
            float wt = __int_as_float(g8[q].y);
#pragma unroll
            for (int r = 0; r < 8; r++) a[r] += bf2f(u[r]) * wt;
        }
        e = en; have = haven;
    }
    for (; e < end; e++) {
        int2 pe = ep[e];
        float wt = __int_as_float(pe.y);
        u16x8 u = *(const u16x8*)&in[(size_t)pe.x * H + l * 8];
#pragma unroll
        for (int r = 0; r < 8; r++) a[r] += bf2f(u[r]) * wt;
    }
    float di = dinv[node];
    u16x8 us = *(const u16x8*)&in[(size_t)node * H + l * 8];
    float dd = di * di;
    u16x8 o;
#pragma unroll
    for (int r = 0; r < 8; r++) o[r] = f2bf(a[r] + bf2f(us[r]) * dd);
    *(u16x8*)&outp[(size_t)node * H + l * 8] = o;
}

// ---------------- aggregation: quarter-wave (16 lanes x ushort8) per node, F=128 ----------------
__global__ __launch_bounds__(256) void gcn_agg128(
        const u16* __restrict__ in, const int* __restrict__ rowp,
        const int2* __restrict__ ep, const float* __restrict__ dinv,
        u16* __restrict__ outp) {
    int node = blockIdx.x * 16 + (threadIdx.x >> 4);
    int l = threadIdx.x & 15;
    int beg = rowp[node], end = rowp[node + 1];
    float a[8] = {};
    int e = beg;
    int2 pr[8];
    bool have = (e + 8 <= end);
    if (have) {
#pragma unroll
        for (int q = 0; q < 8; q++) pr[q] = ep[e + q];
    }
    while (have) {
        int2 g8[8];
#pragma unroll
        for (int q = 0; q < 8; q++) g8[q] = pr[q];
        int en = e + 8;
        bool haven = (en + 8 <= end);
        if (haven) {
#pragma unroll
            for (int q = 0; q < 8; q++) pr[q] = ep[en + q];
        }
#pragma unroll
        for (int q = 0; q < 8; q++) {
            u16x8 u = *(const u16x8*)&in[(size_t)g8[q].x * F_IN + l * 8];
            float wt = __int_as_float(g8[q].y);
#pragma unroll
            for (int r = 0; r < 8; r++) a[r] += bf2f(u[r]) * wt;
        }
        e = en; have = haven;
    }
    for (; e < end; e++) {
        int2 pe = ep[e];
        float wt = __int_as_float(pe.y);
        u16x8 u = *(const u16x8*)&in[(size_t)pe.x * F_IN + l * 8];
#pragma unroll
        for (int r = 0; r < 8; r++) a[r] += bf2f(u[r]) * wt;
    }
    float di = dinv[node];
    u16x8 us = *(const u16x8*)&in[(size_t)node * F_IN + l * 8];
    float dd = di * di;
    u16x8 o;
#pragma unroll
    for (int r = 0; r < 8; r++) o[r] = f2bf(a[r] + bf2f(us[r]) * dd);
    *(u16x8*)&outp[(size_t)node * F_IN + l * 8] = o;
}

// ---------------- MFMA GEMM with bias(+relu) epilogue (node layers, R9 shape) ----------------
template<int K, bool RELU>
__global__ __launch_bounds__(256) void gemm_bias(
        const u16* __restrict__ A,
        const u16* __restrict__ Bhi, const u16* __restrict__ Blo,
        const float* __restrict__ bias, u16* __restrict__ C, int M) {
    __shared__ __align__(16) u16 sA[128 * 40];
    __shared__ __align__(16) u16 sB[2 * 128 * 40];
    const int tid = threadIdx.x;
    const int w = tid >> 6, l = tid & 63;
    const int wm = (w & 1) * 64, wn = (w >> 1) * 64;
    const int bm = blockIdx.x * 128, bn = blockIdx.y * 128;
    const int srow = tid >> 2;
    const int schunk = (tid & 3) * 8;
    const int lr = l & 15, lg = (l >> 4) * 8;

    f32x4 acc[4][4] = {};

    for (int k0 = 0; k0 < K; k0 += 32) {
        {
            int r0 = bm + srow, r1 = bm + srow + 64;
            u16x8 v0 = {}, v1 = {};
            if (r0 < M) v0 = *(const u16x8*)&A[(size_t)r0 * K + k0 + schunk];
            if (r1 < M) v1 = *(const u16x8*)&A[(size_t)r1 * K + k0 + schunk];
            *(u16x8*)&sA[srow * 40 + schunk] = v0;
            *(u16x8*)&sA[(srow + 64) * 40 + schunk] = v1;
        }
        {
            int n0 = bn + srow, n1 = bn + srow + 64;
            *(u16x8*)&sB[srow * 40 + schunk] = *(const u16x8*)&Bhi[(size_t)n0 * K + k0 + schunk];
            *(u16x8*)&sB[(srow + 64) * 40 + schunk] = *(const u16x8*)&Bhi[(size_t)n1 * K + k0 + schunk];
            *(u16x8*)&sB[128 * 40 + srow * 40 + schunk] = *(const u16x8*)&Blo[(size_t)n0 * K + k0 + schunk];
            *(u16x8*)&sB[128 * 40 + (srow + 64) * 40 + schunk] = *(const u16x8*)&Blo[(size_t)n1 * K + k0 + schunk];
        }
        __syncthreads();

        s16x8 af[4], bh[4], bl[4];
#pragma unroll
        for (int i = 0; i < 4; i++)
            af[i] = __builtin_bit_cast(s16x8, *(const u16x8*)&sA[(wm + i * 16 + lr) * 40 + lg]);
#pragma unroll
        for (int j = 0; j < 4; j++) {
            bh[j] = __builtin_bit_cast(s16x8, *(const u16x8*)&sB[(wn + j * 16 + lr) * 40 + lg]);
            bl[j] = __builtin_bit_cast(s16x8, *(const u16x8*)&sB[128 * 40 + (wn + j * 16 + lr) * 40 + lg]);
        }
#pragma unroll
        for (int i = 0; i < 4; i++) {
#pragma unroll
            for (int j = 0; j < 4; j++) {
                acc[i][j] = __builtin_amdgcn_mfma_f32_16x16x32_bf16(af[i], bh[j], acc[i][j], 0, 0, 0);
                acc[i][j] = __builtin_amdgcn_mfma_f32_16x16x32_bf16(af[i], bl[j], acc[i][j], 0, 0, 0);
            }
        }
        __syncthreads();
    }

    float bcol[4];
#pragma unroll
    for (int j = 0; j < 4; j++) bcol[j] = bias[bn + wn + j * 16 + lr];

    const int lq = (l >> 4) * 4;
#pragma unroll
    for (int i = 0; i < 4; i++) {
#pragma unroll
        for (int r0 = 0; r0 < 4; r0++) {
            int row = bm + wm + i * 16 + lq + r0;
            if (row < M) {
#pragma unroll
                for (int j = 0; j < 4; j++) {
                    float v = acc[i][j][r0] + bcol[j];
                    if (RELU) v = fmaxf(v, 0.f);
                    C[(size_t)row * H + bn + wn + j * 16 + lr] = f2bf(v);
                }
            }
        }
    }
}

// ---------------- split-precision MFMA GEMM (MLP tail) ----------------
template<int K, int NW, bool RELU, bool F32OUT>
__global__ __launch_bounds__(256) void gemm_split(
        const u16* __restrict__ Ahi, const u16* __restrict__ Alo,
        const u16* __restrict__ Bhi, const u16* __restrict__ Blo,
        const float* __restrict__ bias,
        u16* __restrict__ Chi, u16* __restrict__ Clo, float* __restrict__ Cf,
        int M) {
    __shared__ __align__(16) u16 sA[2 * 128 * 40];
    __shared__ __align__(16) u16 sB[2 * 128 * 40];
    const int tid = threadIdx.x;
    const int w = tid >> 6, l = tid & 63;
    const int wm = (w & 1) * 64, wn = (w >> 1) * 64;
    const int bm = blockIdx.x * 128, bn = blockIdx.y * 128;
    const int srow = tid >> 2;
    const int schunk = (tid & 3) * 8;
    const int lr = l & 15, lg = (l >> 4) * 8;

    f32x4 acc[4][4] = {};

    for (int k0 = 0; k0 < K; k0 += 32) {
        {
            int r0 = bm + srow, r1 = bm + srow + 64;
            u16x8 v0 = {}, v1 = {}, w0 = {}, w1 = {};
            if (r0 < M) {
                v0 = *(const u16x8*)&Ahi[(size_t)r0 * K + k0 + schunk];
                w0 = *(const u16x8*)&Alo[(size_t)r0 * K + k0 + schunk];
            }
            if (r1 < M) {
                v1 = *(const u16x8*)&Ahi[(size_t)r1 * K + k0 + schunk];
                w1 = *(const u16x8*)&Alo[(size_t)r1 * K + k0 + schunk];
            }
            *(u16x8*)&sA[srow * 40 + schunk] = v0;
            *(u16x8*)&sA[(srow + 64) * 40 + schunk] = v1;
            *(u16x8*)&sA[128 * 40 + srow * 40 + schunk] = w0;
            *(u16x8*)&sA[128 * 40 + (srow + 64) * 40 + schunk] = w1;
        }
        {
            int n0 = bn + srow, n1 = bn + srow + 64;
            *(u16x8*)&sB[srow * 40 + schunk] = *(const u16x8*)&Bhi[(size_t)n0 * K + k0 + schunk];
            *(u16x8*)&sB[(srow + 64) * 40 + schunk] = *(const u16x8*)&Bhi[(size_t)n1 * K + k0 + schunk];
            *(u16x8*)&sB[128 * 40 + srow * 40 + schunk] = *(const u16x8*)&Blo[(size_t)n0 * K + k0 + schunk];
            *(u16x8*)&sB[128 * 40 + (srow + 64) * 40 + schunk] = *(const u16x8*)&Blo[(size_t)n1 * K + k0 + schunk];
        }
        __syncthreads();

        s16x8 af[4], al[4], bh[4], bl[4];
#pragma unroll
        for (int i = 0; i < 4; i++) {
            af[i] = __builtin_bit_cast(s16x8, *(const u16x8*)&sA[(wm + i * 16 + lr) * 40 + lg]);
            al[i] = __builtin_bit_cast(s16x8, *(const u16x8*)&sA[128 * 40 + (wm + i * 16 + lr) * 40 + lg]);
        }
#pragma unroll
        for (int j = 0; j < 4; j++) {
            bh[j] = __builtin_bit_cast(s16x8, *(const u16x8*)&sB[(wn + j * 16 + lr) * 40 + lg]);
            bl[j] = __builtin_bit_cast(s16x8, *(const u16x8*)&sB[128 * 40 + (wn + j * 16 + lr) * 40 + lg]);
        }
#pragma unroll
        for (int i = 0; i < 4; i++) {
#pragma unroll
            for (int j = 0; j < 4; j++) {
                acc[i][j] = __builtin_amdgcn_mfma_f32_16x16x32_bf16(af[i], bh[j], acc[i][j], 0, 0, 0);
                acc[i][j] = __builtin_amdgcn_mfma_f32_16x16x32_bf16(af[i], bl[j], acc[i][j], 0, 0, 0);
                acc[i][j] = __builtin_amdgcn_mfma_f32_16x16x32_bf16(al[i], bh[j], acc[i][j], 0, 0, 0);
            }
        }
        __syncthreads();
    }

    float bcol[4];
#pragma unroll
    for (int j = 0; j < 4; j++) bcol[j] = bias[bn + wn + j * 16 + lr];

    const int lq = (l >> 4) * 4;
#pragma unroll
    for (int i = 0; i < 4; i++) {
#pragma unroll
        for (int r0 = 0; r0 < 4; r0++) {
            int row = bm + wm + i * 16 + lq + r0;
            if (row < M) {
#pragma unroll
                for (int j = 0; j < 4; j++) {
                    float v = acc[i][j][r0] + bcol[j];
                    if (RELU) v = fmaxf(v, 0.f);
                    size_t idx = (size_t)row * NW + bn + wn + j * 16 + lr;
                    if (F32OUT) {
                        Cf[idx] = v;
                    } else {
                        u16 hv = f2bf(v);
                        Chi[idx] = hv;
                        Clo[idx] = f2bf(v - bf2f(hv));
                    }
                }
            }
        }
    }
}

// ---------------- pool: per-graph mean of a3, output hi/lo bf16 split ----------------
__global__ __launch_bounds__(256) void pool_split(
        const u16* __restrict__ a3, const int* __restrict__ goff,
        u16* __restrict__ phi, u16* __restrict__ plo) {
    int g = blockIdx.x, t = threadIdx.x;
    int beg = goff[g], end = goff[g + 1];
    float acc = 0.f;
    int i = beg;
    for (; i + 4 <= end; i += 4) {
        float v0 = bf2f(a3[(size_t)(i + 0) * H + t]);
        float v1 = bf2f(a3[(size_t)(i + 1) * H + t]);
        float v2 = bf2f(a3[(size_t)(i + 2) * H + t]);
        float v3 = bf2f(a3[(size_t)(i + 3) * H + t]);
        acc += (v0 + v1) + (v2 + v3);
    }
    for (; i < end; i++) acc += bf2f(a3[(size_t)i * H + t]);
    acc /= fmaxf((float)(end - beg), 1.f);
    u16 hv = f2bf(acc);
    phi[g * H + t] = hv;
    plo[g * H + t] = f2bf(acc - bf2f(hv));
}

// ---------------- launch ----------------
extern "C" void kernel_launch(void* const* d_in, const int* in_sizes, int n_in,
                              void* d_out, int out_size, void* d_ws, size_t ws_size,
                              hipStream_t stream) {
    const float* x   = (const float*)d_in[0];
    const int*   src = (const int*)d_in[1];
    const int*   dst = (const int*)d_in[2];
    const int*   bat = (const int*)d_in[3];
    const float* W1  = (const float*)d_in[4];  const float* b1  = (const float*)d_in[5];
    const float* W2  = (const float*)d_in[6];  const float* b2  = (const float*)d_in[7];
    const float* W3  = (const float*)d_in[8];  const float* b3  = (const float*)d_in[9];
    const float* Wm1 = (const float*)d_in[10]; const float* bm1 = (const float*)d_in[11];
    const float* Wm2 = (const float*)d_in[12]; const float* bm2 = (const float*)d_in[13];
    float* out = (float*)d_out;

    char* p = (char*)d_ws;
    auto carve = [&](size_t bytes) -> void* {
        void* r = (void*)p;
        p += (bytes + 511) & ~(size_t)511;
        return r;
    };
    u16*   x_bf    = (u16*)  carve((size_t)N_NODES * F_IN * 2);
    u16*   aggX    = (u16*)  carve((size_t)N_NODES * F_IN * 2);
    u16*   bufA    = (u16*)  carve((size_t)N_NODES * H * 2);
    u16*   bufB    = (u16*)  carve((size_t)N_NODES * H * 2);
    float* dinv    = (float*)carve((size_t)N_NODES * 4);
    int*   degc    = (int*)  carve((size_t)N_NODES * 4);
    int*   rowp    = (int*)  carve((size_t)(N_NODES + 1) * 4);
    int*   cur     = (int*)  carve((size_t)N_NODES * 4);
    int*   bcur    = (int*)  carve((size_t)NBUCK * 4);
    int2*  ep      = (int2*) carve((size_t)N_EDGES * 8);
    int2*  ep_stage= (int2*) carve((size_t)N_EDGES * 8);
    u16*   dloc    = (u16*)  carve((size_t)N_EDGES * 2);
    int*   partial = (int*)  carve(4096);
    int*   goff    = (int*)  carve((size_t)(G_GR + 1) * 4);
    u16*   Wt1_hi  = (u16*)  carve((size_t)F_IN * H * 2);
    u16*   Wt1_lo  = (u16*)  carve((size_t)F_IN * H * 2);
    u16*   Wt2_hi  = (u16*)  carve((size_t)H * H * 2);
    u16*   Wt2_lo  = (u16*)  carve((size_t)H * H * 2);
    u16*   Wt3_hi  = (u16*)  carve((size_t)H * H * 2);
    u16*   Wt3_lo  = (u16*)  carve((size_t)H * H * 2);
    u16*   Wm1t_hi = (u16*)  carve((size_t)H * NHID * 2);
    u16*   Wm1t_lo = (u16*)  carve((size_t)H * NHID * 2);
    u16*   Wm2t_hi = (u16*)  carve((size_t)NHID * NOUT * 2);
    u16*   Wm2t_lo = (u16*)  carve((size_t)NHID * NOUT * 2);
    u16*   p_hi    = (u16*)  carve((size_t)G_GR * H * 2);
    u16*   p_lo    = (u16*)  carve((size_t)G_GR * H * 2);
    u16*   y_hi    = (u16*)  carve((size_t)G_GR * H * 2);
    u16*   y_lo    = (u16*)  carve((size_t)G_GR * H * 2);
    u16*   hd_hi   = (u16*)  carve((size_t)G_GR * NHID * 2);
    u16*   hd_lo   = (u16*)  carve((size_t)G_GR * NHID * 2);

    const int NB = (N_NODES + 255) / 256;

    hipMemsetAsync(degc, 0, (size_t)N_NODES * 4, stream);
    prep_head<<<HEAD_BLKS, 256, 0, stream>>>(dst, degc, x, x_bf,
                                             W1, Wt1_hi, Wt1_lo,
                                             W2, Wt2_hi, Wt2_lo,
                                             W3, Wt3_hi, Wt3_lo,
                                             Wm1, Wm1t_hi, Wm1t_lo,
                                             Wm2, Wm2t_hi, Wm2t_lo, bat, goff);
    scan_partial<<<NB, 256, 0, stream>>>(degc, partial);
    scan_offsets<<<1, 512, 0, stream>>>(partial, NB, rowp);
    scan_final_dinv<<<NB, 256, 0, stream>>>(degc, partial, rowp, cur, bcur, dinv);
    // two-phase scatter: bucket staging (sequential streams) then L2-hot redistribute
    scatter_bucket<<<CD_BLKS, 256, 0, stream>>>(src, dst, dinv, bcur, ep_stage, dloc);
    scatter_final<<<NBUCK * 4, 256, 0, stream>>>(rowp, cur, ep_stage, dloc, ep);

    dim3 ggrid((N_NODES + 127) / 128, 2);

    // layer 1: aggregate-first (256B rows), then transform+bias+relu
    gcn_agg128<<<N_NODES / 16, 256, 0, stream>>>(x_bf, rowp, ep, dinv, aggX);
    gemm_bias<F_IN, true><<<ggrid, 256, 0, stream>>>(aggX, Wt1_hi, Wt1_lo, b1, bufA, N_NODES);
    // layer 2
    gcn_agg256<<<N_NODES / 8, 256, 0, stream>>>(bufA, rowp, ep, dinv, bufB);
    gemm_bias<H, true><<<ggrid, 256, 0, stream>>>(bufB, Wt2_hi, Wt2_lo, b2, bufA, N_NODES);
    // layer 3: aggregate only; W3+b3 folded into pooled domain
    gcn_agg256<<<N_NODES / 8, 256, 0, stream>>>(bufA, rowp, ep, dinv, bufB);

    // tail: pool -> y=pW3+b3 -> hidden=relu(yWm1+bm1) -> out=hidden Wm2+bm2
    pool_split<<<G_GR, 256, 0, stream>>>(bufB, goff, p_hi, p_lo);
    dim3 g3(2, 2), gm1(2, 4), gm2(2, 2);
    gemm_split<H, H, false, false><<<g3, 256, 0, stream>>>(
        p_hi, p_lo, Wt3_hi, Wt3_lo, b3, y_hi, y_lo, nullptr, G_GR);
    gemm_split<H, NHID, true, false><<<gm1, 256, 0, stream>>>(
        y_hi, y_lo, Wm1t_hi, Wm1t_lo, bm1, hd_hi, hd_lo, nullptr, G_GR);
    gemm_split<NHID, NOUT, false, true><<<gm2, 256, 0, stream>>>(
        hd_hi, hd_lo, Wm2t_hi, Wm2t_lo, bm2, nullptr, nullptr, out, G_GR);
}

// Round 12
// 808.574 us; speedup vs baseline: 1.9872x; 1.9872x over previous
//
#include <hip/hip_runtime.h>
#include <hip/hip_bf16.h>

#define N_NODES 100000
#define N_EDGES 1600000
#define F_IN    128
#define H       256
#define NHID    512
#define NOUT    256
#define G_GR    256

typedef unsigned short u16;
typedef __attribute__((ext_vector_type(8))) short s16x8;
typedef __attribute__((ext_vector_type(8))) unsigned short u16x8;
typedef __attribute__((ext_vector_type(4))) float f32x4;

__device__ __forceinline__ float bf2f(u16 u) {
    union { unsigned int i; float f; } v; v.i = ((unsigned int)u) << 16; return v.f;
}
__device__ __forceinline__ u16 f2bf(float f) {
    union { float f; unsigned int i; } v; v.f = f;
    unsigned int x = v.i;
    x += 0x7fffu + ((x >> 16) & 1u);
    return (u16)(x >> 16);
}

// ---------------- head: count_deg (atomics) fused with streaming converts ----------------
#define CD_BLKS   1563                        // 4 consecutive edges/thread, int4 loads
#define SPX_BLKS  ((N_NODES * F_IN) / 1024)
#define T1_BLKS   ((F_IN * H) / 256)
#define T2_BLKS   ((H * H) / 256)
#define T3_BLKS   ((H * H) / 256)
#define TM1_BLKS  ((H * NHID) / 256)
#define TM2_BLKS  ((NHID * NOUT) / 256)
#define HEAD_BLKS (CD_BLKS + SPX_BLKS + T1_BLKS + T2_BLKS + T3_BLKS + TM1_BLKS + TM2_BLKS + 2)

__device__ __forceinline__ void transpose_split_body(const float* __restrict__ W,
        u16* __restrict__ thi, u16* __restrict__ tlo, int K, int N, int id) {
    int n = id / K, k = id - n * K;
    float f = W[(size_t)k * N + n];
    u16 h = f2bf(f);
    thi[id] = h;
    tlo[id] = f2bf(f - bf2f(h));
}

__global__ __launch_bounds__(256) void prep_head(
        const int* __restrict__ dst, int* __restrict__ degc,
        const float* __restrict__ x, u16* __restrict__ x_bf,
        const float* __restrict__ W1, u16* __restrict__ t1h, u16* __restrict__ t1l,
        const float* __restrict__ W2, u16* __restrict__ t2h, u16* __restrict__ t2l,
        const float* __restrict__ W3, u16* __restrict__ t3h, u16* __restrict__ t3l,
        const float* __restrict__ Wm1, u16* __restrict__ tm1h, u16* __restrict__ tm1l,
        const float* __restrict__ Wm2, u16* __restrict__ tm2h, u16* __restrict__ tm2l,
        const int* __restrict__ batch, int* __restrict__ goff) {
    int bid = blockIdx.x;
    if (bid < CD_BLKS) {
        int base = (bid * 256 + threadIdx.x) * 4;
        if (base + 4 <= N_EDGES) {
            int4 d4 = *(const int4*)&dst[base];
            atomicAdd(&degc[d4.x], 1);
            atomicAdd(&degc[d4.y], 1);
            atomicAdd(&degc[d4.z], 1);
            atomicAdd(&degc[d4.w], 1);
        } else {
            for (int e = base; e < N_EDGES; e++) atomicAdd(&degc[dst[e]], 1);
        }
        return;
    }
    bid -= CD_BLKS;
    if (bid < SPX_BLKS) {
        int idx = bid * 256 + threadIdx.x;
        float4 f = *(const float4*)&x[(size_t)idx * 4];
        ushort4 o;
        o.x = f2bf(f.x); o.y = f2bf(f.y); o.z = f2bf(f.z); o.w = f2bf(f.w);
        *(ushort4*)&x_bf[(size_t)idx * 4] = o;
        return;
    }
    bid -= SPX_BLKS;
    if (bid < T1_BLKS) {
        transpose_split_body(W1, t1h, t1l, F_IN, H, bid * 256 + threadIdx.x);
        return;
    }
    bid -= T1_BLKS;
    if (bid < T2_BLKS) {
        transpose_split_body(W2, t2h, t2l, H, H, bid * 256 + threadIdx.x);
        return;
    }
    bid -= T2_BLKS;
    if (bid < T3_BLKS) {
        transpose_split_body(W3, t3h, t3l, H, H, bid * 256 + threadIdx.x);
        return;
    }
    bid -= T3_BLKS;
    if (bid < TM1_BLKS) {
        transpose_split_body(Wm1, tm1h, tm1l, H, NHID, bid * 256 + threadIdx.x);
        return;
    }
    bid -= TM1_BLKS;
    if (bid < TM2_BLKS) {
        transpose_split_body(Wm2, tm2h, tm2l, NHID, NOUT, bid * 256 + threadIdx.x);
        return;
    }
    bid -= TM2_BLKS;
    {
        int g = bid * 256 + threadIdx.x;
        if (g > G_GR) return;
        int lo = 0, hi = N_NODES;
        while (lo < hi) {
            int mid = (lo + hi) >> 1;
            if (batch[mid] < g) lo = mid + 1; else hi = mid;
        }
        goff[g] = lo;
    }
}

// ---------------- scan (CSR rowp) ----------------
__global__ void scan_partial(const int* __restrict__ cnt, int* __restrict__ partial) {
    __shared__ int s[256];
    int t = threadIdx.x;
    int i = blockIdx.x * 256 + t;
    int v = (i < N_NODES) ? cnt[i] : 0;
    s[t] = v; __syncthreads();
    for (int off = 128; off > 0; off >>= 1) {
        if (t < off) s[t] += s[t + off];
        __syncthreads();
    }
    if (t == 0) partial[blockIdx.x] = s[0];
}

__global__ void scan_offsets(int* __restrict__ partial, int nb, int* __restrict__ rowp) {
    __shared__ int s[512];
    int t = threadIdx.x;
    int orig = (t < nb) ? partial[t] : 0;
    s[t] = orig; __syncthreads();
    for (int off = 1; off < 512; off <<= 1) {
        int u = (t >= off) ? s[t - off] : 0;
        __syncthreads();
        s[t] += u;
        __syncthreads();
    }
    if (t < nb) partial[t] = s[t] - orig;
    if (t == 0) rowp[N_NODES] = N_EDGES;
}

__global__ void scan_final_dinv(const int* __restrict__ cnt, const int* __restrict__ partial,
                                int* __restrict__ rowp, int* __restrict__ cur,
                                float* __restrict__ dinv) {
    __shared__ int s[256];
    int t = threadIdx.x;
    int i = blockIdx.x * 256 + t;
    int v = (i < N_NODES) ? cnt[i] : 0;
    s[t] = v; __syncthreads();
    for (int off = 1; off < 256; off <<= 1) {
        int u = (t >= off) ? s[t - off] : 0;
        __syncthreads();
        s[t] += u;
        __syncthreads();
    }
    if (i < N_NODES) {
        int r = partial[blockIdx.x] + s[t] - v;
        rowp[i] = r;
        cur[i] = r;
        dinv[i] = rsqrtf(1.0f + (float)v);
    }
}

// ---------------- edge scatter: {src, w} pairs; 4 consecutive edges/thread, batched ILP ----
__global__ __launch_bounds__(256) void scatter_edges(
        const int* __restrict__ src, const int* __restrict__ dst,
        const float* __restrict__ dinv, int* __restrict__ cur,
        int2* __restrict__ ep) {
    int base = (blockIdx.x * 256 + threadIdx.x) * 4;
    if (base + 4 <= N_EDGES) {
        int4 d4 = *(const int4*)&dst[base];
        int4 s4 = *(const int4*)&src[base];
        float w0 = dinv[d4.x] * dinv[s4.x];
        float w1 = dinv[d4.y] * dinv[s4.y];
        float w2 = dinv[d4.z] * dinv[s4.z];
        float w3 = dinv[d4.w] * dinv[s4.w];
        int p0 = atomicAdd(&cur[d4.x], 1);
        int p1 = atomicAdd(&cur[d4.y], 1);
        int p2 = atomicAdd(&cur[d4.z], 1);
        int p3 = atomicAdd(&cur[d4.w], 1);
        int2 v0; v0.x = s4.x; v0.y = __float_as_int(w0);
        int2 v1; v1.x = s4.y; v1.y = __float_as_int(w1);
        int2 v2; v2.x = s4.z; v2.y = __float_as_int(w2);
        int2 v3; v3.x = s4.w; v3.y = __float_as_int(w3);
        ep[p0] = v0;
        ep[p1] = v1;
        ep[p2] = v2;
        ep[p3] = v3;
    } else {
        for (int e = base; e < N_EDGES; e++) {
            int d = dst[e];
            int s = src[e];
            float w = dinv[d] * dinv[s];
            int pos = atomicAdd(&cur[d], 1);
            int2 v; v.x = s; v.y = __float_as_int(w);
            ep[pos] = v;
        }
    }
}

// ---------------- aggregation: half-wave (32 lanes x ushort8) per node, H=256 ----------------
__global__ __launch_bounds__(256) void gcn_agg256(
        const u16* __restrict__ in, const int* __restrict__ rowp,
        const int2* __restrict__ ep, const float* __restrict__ dinv,
        u16* __restrict__ outp) {
    int node = blockIdx.x * 8 + (threadIdx.x >> 5);
    int l = threadIdx.x & 31;
    int beg = rowp[node], end = rowp[node + 1];
    float a[8] = {};
    int e = beg;
    int2 pr[8];
    bool have = (e + 8 <= end);
    if (have) {
#pragma unroll
        for (int q = 0; q < 8; q++) pr[q] = ep[e + q];
    }
    while (have) {
        int2 g8[8];
#pragma unroll
        for (int q = 0; q < 8; q++) g8[q] = pr[q];
        int en = e + 8;
        bool haven = (en + 8 <= end);
        if (haven) {
#pragma unroll
            for (int q = 0; q < 8; q++) pr[q] = ep[en + q];
        }
#pragma unroll
        for (int q = 0; q < 8; q++) {
            u16x8 u = *(const u16x8*)&in[(size_t)g8[q].x * H + l * 8];
            float wt = __int_as_float(g8[q].y);
#pragma unroll
            for (int r = 0; r < 8; r++) a[r] += bf2f(u[r]) * wt;
        }
        e = en; have = haven;
    }
    for (; e < end; e++) {
        int2 pe = ep[e];
        float wt = __int_as_float(pe.y);
        u16x8 u = *(const u16x8*)&in[(size_t)pe.x * H + l * 8];
#pragma unroll
        for (int r = 0; r < 8; r++) a[r] += bf2f(u[r]) * wt;
    }
    float di = dinv[node];
    u16x8 us = *(const u16x8*)&in[(size_t)node * H + l * 8];
    float dd = di * di;
    u16x8 o;
#pragma unroll
    for (int r = 0; r < 8; r++) o[r] = f2bf(a[r] + bf2f(us[r]) * dd);
    *(u16x8*)&outp[(size_t)node * H + l * 8] = o;
}

// ---------------- aggregation: quarter-wave (16 lanes x ushort8) per node, F=128 ----------------
__global__ __launch_bounds__(256) void gcn_agg128(
        const u16* __restrict__ in, const int* __restrict__ rowp,
        const int2* __restrict__ ep, const float* __restrict__ dinv,
        u16* __restrict__ outp) {
    int node = blockIdx.x * 16 + (threadIdx.x >> 4);
    int l = threadIdx.x & 15;
    int beg = rowp[node], end = rowp[node + 1];
    float a[8] = {};
    int e = beg;
    int2 pr[8];
    bool have = (e + 8 <= end);
    if (have) {
#pragma unroll
        for (int q = 0; q < 8; q++) pr[q] = ep[e + q];
    }
    while (have) {
        int2 g8[8];
#pragma unroll
        for (int q = 0; q < 8; q++) g8[q] = pr[q];
        int en = e + 8;
        bool haven = (en + 8 <= end);
        if (haven) {
#pragma unroll
            for (int q = 0; q < 8; q++) pr[q] = ep[en + q];
        }
#pragma unroll
        for (int q = 0; q < 8; q++) {
            u16x8 u = *(const u16x8*)&in[(size_t)g8[q].x * F_IN + l * 8];
            float wt = __int_as_float(g8[q].y);
#pragma unroll
            for (int r = 0; r < 8; r++) a[r] += bf2f(u[r]) * wt;
        }
        e = en; have = haven;
    }
    for (; e < end; e++) {
        int2 pe = ep[e];
        float wt = __int_as_float(pe.y);
        u16x8 u = *(const u16x8*)&in[(size_t)pe.x * F_IN + l * 8];
#pragma unroll
        for (int r = 0; r < 8; r++) a[r] += bf2f(u[r]) * wt;
    }
    float di = dinv[node];
    u16x8 us = *(const u16x8*)&in[(size_t)node * F_IN + l * 8];
    float dd = di * di;
    u16x8 o;
#pragma unroll
    for (int r = 0; r < 8; r++) o[r] = f2bf(a[r] + bf2f(us[r]) * dd);
    *(u16x8*)&outp[(size_t)node * F_IN + l * 8] = o;
}

// ---------------- MFMA GEMM with bias(+relu) epilogue (node layers) ----------------
template<int K, bool RELU>
__global__ __launch_bounds__(256) void gemm_bias(
        const u16* __restrict__ A,
        const u16* __restrict__ Bhi, const u16* __restrict__ Blo,
        const float* __restrict__ bias, u16* __restrict__ C, int M) {
    __shared__ __align__(16) u16 sA[128 * 40];
    __shared__ __align__(16) u16 sB[2 * 128 * 40];
    const int tid = threadIdx.x;
    const int w = tid >> 6, l = tid & 63;
    const int wm = (w & 1) * 64, wn = (w >> 1) * 64;
    const int bm = blockIdx.x * 128, bn = blockIdx.y * 128;
    const int srow = tid >> 2;
    const int schunk = (tid & 3) * 8;
    const int lr = l & 15, lg = (l >> 4) * 8;

    f32x4 acc[4][4] = {};

    for (int k0 = 0; k0 < K; k0 += 32) {
        {
            int r0 = bm + srow, r1 = bm + srow + 64;
            u16x8 v0 = {}, v1 = {};
            if (r0 < M) v0 = *(const u16x8*)&A[(size_t)r0 * K + k0 + schunk];
            if (r1 < M) v1 = *(const u16x8*)&A[(size_t)r1 * K + k0 + schunk];
            *(u16x8*)&sA[srow * 40 + schunk] = v0;
            *(u16x8*)&sA[(srow + 64) * 40 + schunk] = v1;
        }
        {
            int n0 = bn + srow, n1 = bn + srow + 64;
            *(u16x8*)&sB[srow * 40 + schunk] = *(const u16x8*)&Bhi[(size_t)n0 * K + k0 + schunk];
            *(u16x8*)&sB[(srow + 64) * 40 + schunk] = *(const u16x8*)&Bhi[(size_t)n1 * K + k0 + schunk];
            *(u16x8*)&sB[128 * 40 + srow * 40 + schunk] = *(const u16x8*)&Blo[(size_t)n0 * K + k0 + schunk];
            *(u16x8*)&sB[128 * 40 + (srow + 64) * 40 + schunk] = *(const u16x8*)&Blo[(size_t)n1 * K + k0 + schunk];
        }
        __syncthreads();

        s16x8 af[4], bh[4], bl[4];
#pragma unroll
        for (int i = 0; i < 4; i++)
            af[i] = __builtin_bit_cast(s16x8, *(const u16x8*)&sA[(wm + i * 16 + lr) * 40 + lg]);
#pragma unroll
        for (int j = 0; j < 4; j++) {
            bh[j] = __builtin_bit_cast(s16x8, *(const u16x8*)&sB[(wn + j * 16 + lr) * 40 + lg]);
            bl[j] = __builtin_bit_cast(s16x8, *(const u16x8*)&sB[128 * 40 + (wn + j * 16 + lr) * 40 + lg]);
        }
#pragma unroll
        for (int i = 0; i < 4; i++) {
#pragma unroll
            for (int j = 0; j < 4; j++) {
                acc[i][j] = __builtin_amdgcn_mfma_f32_16x16x32_bf16(af[i], bh[j], acc[i][j], 0, 0, 0);
                acc[i][j] = __builtin_amdgcn_mfma_f32_16x16x32_bf16(af[i], bl[j], acc[i][j], 0, 0, 0);
            }
        }
        __syncthreads();
    }

    float bcol[4];
#pragma unroll
    for (int j = 0; j < 4; j++) bcol[j] = bias[bn + wn + j * 16 + lr];

    const int lq = (l >> 4) * 4;
#pragma unroll
    for (int i = 0; i < 4; i++) {
#pragma unroll
        for (int r0 = 0; r0 < 4; r0++) {
            int row = bm + wm + i * 16 + lq + r0;
            if (row < M) {
#pragma unroll
                for (int j = 0; j < 4; j++) {
                    float v = acc[i][j][r0] + bcol[j];
                    if (RELU) v = fmaxf(v, 0.f);
                    C[(size_t)row * H + bn + wn + j * 16 + lr] = f2bf(v);
                }
            }
        }
    }
}

// ---------------- split-precision MFMA GEMM (MLP tail) ----------------
template<int K, int NW, bool RELU, bool F32OUT>
__global__ __launch_bounds__(256) void gemm_split(
        const u16* __restrict__ Ahi, const u16* __restrict__ Alo,
        const u16* __restrict__ Bhi, const u16* __restrict__ Blo,
        const float* __restrict__ bias,
        u16* __restrict__ Chi, u16* __restrict__ Clo, float* __restrict__ Cf,
        int M) {
    __shared__ __align__(16) u16 sA[2 * 128 * 40];
    __shared__ __align__(16) u16 sB[2 * 128 * 40];
    const int tid = threadIdx.x;
    const int w = tid >> 6, l = tid & 63;
    const int wm = (w & 1) * 64, wn = (w >> 1) * 64;
    const int bm = blockIdx.x * 128, bn = blockIdx.y * 128;
    const int srow = tid >> 2;
    const int schunk = (tid & 3) * 8;
    const int lr = l & 15, lg = (l >> 4) * 8;

    f32x4 acc[4][4] = {};

    for (int k0 = 0; k0 < K; k0 += 32) {
        {
            int r0 = bm + srow, r1 = bm + srow + 64;
            u16x8 v0 = {}, v1 = {}, w0 = {}, w1 = {};
            if (r0 < M) {
                v0 = *(const u16x8*)&Ahi[(size_t)r0 * K + k0 + schunk];
                w0 = *(const u16x8*)&Alo[(size_t)r0 * K + k0 + schunk];
            }
            if (r1 < M) {
                v1 = *(const u16x8*)&Ahi[(size_t)r1 * K + k0 + schunk];
                w1 = *(const u16x8*)&Alo[(size_t)r1 * K + k0 + schunk];
            }
            *(u16x8*)&sA[srow * 40 + schunk] = v0;
            *(u16x8*)&sA[(srow + 64) * 40 + schunk] = v1;
            *(u16x8*)&sA[128 * 40 + srow * 40 + schunk] = w0;
            *(u16x8*)&sA[128 * 40 + (srow + 64) * 40 + schunk] = w1;
        }
        {
            int n0 = bn + srow, n1 = bn + srow + 64;
            *(u16x8*)&sB[srow * 40 + schunk] = *(const u16x8*)&Bhi[(size_t)n0 * K + k0 + schunk];
            *(u16x8*)&sB[(srow + 64) * 40 + schunk] = *(const u16x8*)&Bhi[(size_t)n1 * K + k0 + schunk];
            *(u16x8*)&sB[128 * 40 + srow * 40 + schunk] = *(const u16x8*)&Blo[(size_t)n0 * K + k0 + schunk];
            *(u16x8*)&sB[128 * 40 + (srow + 64) * 40 + schunk] = *(const u16x8*)&Blo[(size_t)n1 * K + k0 + schunk];
        }
        __syncthreads();

        s16x8 af[4], al[4], bh[4], bl[4];
#pragma unroll
        for (int i = 0; i < 4; i++) {
            af[i] = __builtin_bit_cast(s16x8, *(const u16x8*)&sA[(wm + i * 16 + lr) * 40 + lg]);
            al[i] = __builtin_bit_cast(s16x8, *(const u16x8*)&sA[128 * 40 + (wm + i * 16 + lr) * 40 + lg]);
        }
#pragma unroll
        for (int j = 0; j < 4; j++) {
            bh[j] = __builtin_bit_cast(s16x8, *(const u16x8*)&sB[(wn + j * 16 + lr) * 40 + lg]);
            bl[j] = __builtin_bit_cast(s16x8, *(const u16x8*)&sB[128 * 40 + (wn + j * 16 + lr) * 40 + lg]);
        }
#pragma unroll
        for (int i = 0; i < 4; i++) {
#pragma unroll
            for (int j = 0; j < 4; j++) {
                acc[i][j] = __builtin_amdgcn_mfma_f32_16x16x32_bf16(af[i], bh[j], acc[i][j], 0, 0, 0);
                acc[i][j] = __builtin_amdgcn_mfma_f32_16x16x32_bf16(af[i], bl[j], acc[i][j], 0, 0, 0);
                acc[i][j] = __builtin_amdgcn_mfma_f32_16x16x32_bf16(al[i], bh[j], acc[i][j], 0, 0, 0);
            }
        }
        __syncthreads();
    }

    float bcol[4];
#pragma unroll
    for (int j = 0; j < 4; j++) bcol[j] = bias[bn + wn + j * 16 + lr];

    const int lq = (l >> 4) * 4;
#pragma unroll
    for (int i = 0; i < 4; i++) {
#pragma unroll
        for (int r0 = 0; r0 < 4; r0++) {
            int row = bm + wm + i * 16 + lq + r0;
            if (row < M) {
#pragma unroll
                for (int j = 0; j < 4; j++) {
                    float v = acc[i][j][r0] + bcol[j];
                    if (RELU) v = fmaxf(v, 0.f);
                    size_t idx = (size_t)row * NW + bn + wn + j * 16 + lr;
                    if (F32OUT) {
                        Cf[idx] = v;
                    } else {
                        u16 hv = f2bf(v);
                        Chi[idx] = hv;
                        Clo[idx] = f2bf(v - bf2f(hv));
                    }
                }
            }
        }
    }
}

// ---------------- pool: per-graph mean of a3, output hi/lo bf16 split ----------------
__global__ __launch_bounds__(256) void pool_split(
        const u16* __restrict__ a3, const int* __restrict__ goff,
        u16* __restrict__ phi, u16* __restrict__ plo) {
    int g = blockIdx.x, t = threadIdx.x;
    int beg = goff[g], end = goff[g + 1];
    float acc = 0.f;
    int i = beg;
    for (; i + 4 <= end; i += 4) {
        float v0 = bf2f(a3[(size_t)(i + 0) * H + t]);
        float v1 = bf2f(a3[(size_t)(i + 1) * H + t]);
        float v2 = bf2f(a3[(size_t)(i + 2) * H + t]);
        float v3 = bf2f(a3[(size_t)(i + 3) * H + t]);
        acc += (v0 + v1) + (v2 + v3);
    }
    for (; i < end; i++) acc += bf2f(a3[(size_t)i * H + t]);
    acc /= fmaxf((float)(end - beg), 1.f);
    u16 hv = f2bf(acc);
    phi[g * H + t] = hv;
    plo[g * H + t] = f2bf(acc - bf2f(hv));
}

// ---------------- launch ----------------
extern "C" void kernel_launch(void* const* d_in, const int* in_sizes, int n_in,
                              void* d_out, int out_size, void* d_ws, size_t ws_size,
                              hipStream_t stream) {
    const float* x   = (const float*)d_in[0];
    const int*   src = (const int*)d_in[1];
    const int*   dst = (const int*)d_in[2];
    const int*   bat = (const int*)d_in[3];
    const float* W1  = (const float*)d_in[4];  const float* b1  = (const float*)d_in[5];
    const float* W2  = (const float*)d_in[6];  const float* b2  = (const float*)d_in[7];
    const float* W3  = (const float*)d_in[8];  const float* b3  = (const float*)d_in[9];
    const float* Wm1 = (const float*)d_in[10]; const float* bm1 = (const float*)d_in[11];
    const float* Wm2 = (const float*)d_in[12]; const float* bm2 = (const float*)d_in[13];
    float* out = (float*)d_out;

    char* p = (char*)d_ws;
    auto carve = [&](size_t bytes) -> void* {
        void* r = (void*)p;
        p += (bytes + 511) & ~(size_t)511;
        return r;
    };
    u16*   x_bf    = (u16*)  carve((size_t)N_NODES * F_IN * 2);
    u16*   aggX    = (u16*)  carve((size_t)N_NODES * F_IN * 2);
    u16*   bufA    = (u16*)  carve((size_t)N_NODES * H * 2);
    u16*   bufB    = (u16*)  carve((size_t)N_NODES * H * 2);
    float* dinv    = (float*)carve((size_t)N_NODES * 4);
    int*   degc    = (int*)  carve((size_t)N_NODES * 4);
    int*   rowp    = (int*)  carve((size_t)(N_NODES + 1) * 4);
    int*   cur     = (int*)  carve((size_t)N_NODES * 4);
    int2*  ep      = (int2*) carve((size_t)N_EDGES * 8);
    int*   partial = (int*)  carve(4096);
    int*   goff    = (int*)  carve((size_t)(G_GR + 1) * 4);
    u16*   Wt1_hi  = (u16*)  carve((size_t)F_IN * H * 2);
    u16*   Wt1_lo  = (u16*)  carve((size_t)F_IN * H * 2);
    u16*   Wt2_hi  = (u16*)  carve((size_t)H * H * 2);
    u16*   Wt2_lo  = (u16*)  carve((size_t)H * H * 2);
    u16*   Wt3_hi  = (u16*)  carve((size_t)H * H * 2);
    u16*   Wt3_lo  = (u16*)  carve((size_t)H * H * 2);
    u16*   Wm1t_hi = (u16*)  carve((size_t)H * NHID * 2);
    u16*   Wm1t_lo = (u16*)  carve((size_t)H * NHID * 2);
    u16*   Wm2t_hi = (u16*)  carve((size_t)NHID * NOUT * 2);
    u16*   Wm2t_lo = (u16*)  carve((size_t)NHID * NOUT * 2);
    u16*   p_hi    = (u16*)  carve((size_t)G_GR * H * 2);
    u16*   p_lo    = (u16*)  carve((size_t)G_GR * H * 2);
    u16*   y_hi    = (u16*)  carve((size_t)G_GR * H * 2);
    u16*   y_lo    = (u16*)  carve((size_t)G_GR * H * 2);
    u16*   hd_hi   = (u16*)  carve((size_t)G_GR * NHID * 2);
    u16*   hd_lo   = (u16*)  carve((size_t)G_GR * NHID * 2);

    const int NB = (N_NODES + 255) / 256;

    hipMemsetAsync(degc, 0, (size_t)N_NODES * 4, stream);
    prep_head<<<HEAD_BLKS, 256, 0, stream>>>(dst, degc, x, x_bf,
                                             W1, Wt1_hi, Wt1_lo,
                                             W2, Wt2_hi, Wt2_lo,
                                             W3, Wt3_hi, Wt3_lo,
                                             Wm1, Wm1t_hi, Wm1t_lo,
                                             Wm2, Wm2t_hi, Wm2t_lo, bat, goff);
    scan_partial<<<NB, 256, 0, stream>>>(degc, partial);
    scan_offsets<<<1, 512, 0, stream>>>(partial, NB, rowp);
    scan_final_dinv<<<NB, 256, 0, stream>>>(degc, partial, rowp, cur, dinv);
    scatter_edges<<<CD_BLKS, 256, 0, stream>>>(src, dst, dinv, cur, ep);

    dim3 ggrid((N_NODES + 127) / 128, 2);

    // layer 1: aggregate-first (256B rows), then transform+bias+relu
    gcn_agg128<<<N_NODES / 16, 256, 0, stream>>>(x_bf, rowp, ep, dinv, aggX);
    gemm_bias<F_IN, true><<<ggrid, 256, 0, stream>>>(aggX, Wt1_hi, Wt1_lo, b1, bufA, N_NODES);
    // layer 2
    gcn_agg256<<<N_NODES / 8, 256, 0, stream>>>(bufA, rowp, ep, dinv, bufB);
    gemm_bias<H, true><<<ggrid, 256, 0, stream>>>(bufB, Wt2_hi, Wt2_lo, b2, bufA, N_NODES);
    // layer 3: aggregate only; W3+b3 folded into pooled domain
    gcn_agg256<<<N_NODES / 8, 256, 0, stream>>>(bufA, rowp, ep, dinv, bufB);

    // tail: pool -> y=pW3+b3 -> hidden=relu(yWm1+bm1) -> out=hidden Wm2+bm2
    pool_split<<<G_GR, 256, 0, stream>>>(bufB, goff, p_hi, p_lo);
    dim3 g3(2, 2), gm1(2, 4), gm2(2, 2);
    gemm_split<H, H, false, false><<<g3, 256, 0, stream>>>(
        p_hi, p_lo, Wt3_hi, Wt3_lo, b3, y_hi, y_lo, nullptr, G_GR);
    gemm_split<H, NHID, true, false><<<gm1, 256, 0, stream>>>(
        y_hi, y_lo, Wm1t_hi, Wm1t_lo, bm1, hd_hi, hd_lo, nullptr, G_GR);
    gemm_split<NHID, NOUT, false, true><<<gm2, 256, 0, stream>>>(
        hd_hi, hd_lo, Wm2t_hi, Wm2t_lo, bm2, nullptr, nullptr, out, G_GR);
}

// Round 13
// 749.344 us; speedup vs baseline: 2.1442x; 1.0790x over previous
//
#include <hip/hip_runtime.h>
#include <hip/hip_bf16.h>

#define N_NODES 100000
#define N_EDGES 1600000
#define F_IN    128
#define H       256
#define NHID    512
#define NOUT    256
#define G_GR    256

typedef unsigned short u16;
typedef __attribute__((ext_vector_type(8))) short s16x8;
typedef __attribute__((ext_vector_type(8))) unsigned short u16x8;
typedef __attribute__((ext_vector_type(4))) float f32x4;

__device__ __forceinline__ float bf2f(u16 u) {
    union { unsigned int i; float f; } v; v.i = ((unsigned int)u) << 16; return v.f;
}
__device__ __forceinline__ u16 f2bf(float f) {
    union { float f; unsigned int i; } v; v.f = f;
    unsigned int x = v.i;
    x += 0x7fffu + ((x >> 16) & 1u);
    return (u16)(x >> 16);
}

// ---------------- head: count_deg (atomics, R8 strided form) + weight transposes + goff -----
#define CD_BLKS   1563                        // 4 strided edges/thread (R8 known-good form)
#define SPX_BLKS  ((N_NODES * F_IN) / 1024)   // 12500 — now carried by scatter kernel
#define T1_BLKS   ((F_IN * H) / 256)
#define T2_BLKS   ((H * H) / 256)
#define T3_BLKS   ((H * H) / 256)
#define TM1_BLKS  ((H * NHID) / 256)
#define TM2_BLKS  ((NHID * NOUT) / 256)
#define HEAD_BLKS (CD_BLKS + T1_BLKS + T2_BLKS + T3_BLKS + TM1_BLKS + TM2_BLKS + 2)

__device__ __forceinline__ void transpose_split_body(const float* __restrict__ W,
        u16* __restrict__ thi, u16* __restrict__ tlo, int K, int N, int id) {
    int n = id / K, k = id - n * K;
    float f = W[(size_t)k * N + n];
    u16 h = f2bf(f);
    thi[id] = h;
    tlo[id] = f2bf(f - bf2f(h));
}

__global__ __launch_bounds__(256) void prep_head(
        const int* __restrict__ dst, int* __restrict__ degc,
        const float* __restrict__ W1, u16* __restrict__ t1h, u16* __restrict__ t1l,
        const float* __restrict__ W2, u16* __restrict__ t2h, u16* __restrict__ t2l,
        const float* __restrict__ W3, u16* __restrict__ t3h, u16* __restrict__ t3l,
        const float* __restrict__ Wm1, u16* __restrict__ tm1h, u16* __restrict__ tm1l,
        const float* __restrict__ Wm2, u16* __restrict__ tm2h, u16* __restrict__ tm2l,
        const int* __restrict__ batch, int* __restrict__ goff) {
    int bid = blockIdx.x;
    if (bid < CD_BLKS) {
        int base = bid * 1024 + threadIdx.x;
#pragma unroll
        for (int q = 0; q < 4; q++) {
            int e = base + q * 256;
            if (e < N_EDGES) atomicAdd(&degc[dst[e]], 1);
        }
        return;
    }
    bid -= CD_BLKS;
    if (bid < T1_BLKS) {
        transpose_split_body(W1, t1h, t1l, F_IN, H, bid * 256 + threadIdx.x);
        return;
    }
    bid -= T1_BLKS;
    if (bid < T2_BLKS) {
        transpose_split_body(W2, t2h, t2l, H, H, bid * 256 + threadIdx.x);
        return;
    }
    bid -= T2_BLKS;
    if (bid < T3_BLKS) {
        transpose_split_body(W3, t3h, t3l, H, H, bid * 256 + threadIdx.x);
        return;
    }
    bid -= T3_BLKS;
    if (bid < TM1_BLKS) {
        transpose_split_body(Wm1, tm1h, tm1l, H, NHID, bid * 256 + threadIdx.x);
        return;
    }
    bid -= TM1_BLKS;
    if (bid < TM2_BLKS) {
        transpose_split_body(Wm2, tm2h, tm2l, NHID, NOUT, bid * 256 + threadIdx.x);
        return;
    }
    bid -= TM2_BLKS;
    {
        int g = bid * 256 + threadIdx.x;
        if (g > G_GR) return;
        int lo = 0, hi = N_NODES;
        while (lo < hi) {
            int mid = (lo + hi) >> 1;
            if (batch[mid] < g) lo = mid + 1; else hi = mid;
        }
        goff[g] = lo;
    }
}

// ---------------- scan (CSR rowp) ----------------
__global__ void scan_partial(const int* __restrict__ cnt, int* __restrict__ partial) {
    __shared__ int s[256];
    int t = threadIdx.x;
    int i = blockIdx.x * 256 + t;
    int v = (i < N_NODES) ? cnt[i] : 0;
    s[t] = v; __syncthreads();
    for (int off = 128; off > 0; off >>= 1) {
        if (t < off) s[t] += s[t + off];
        __syncthreads();
    }
    if (t == 0) partial[blockIdx.x] = s[0];
}

__global__ void scan_offsets(int* __restrict__ partial, int nb, int* __restrict__ rowp) {
    __shared__ int s[512];
    int t = threadIdx.x;
    int orig = (t < nb) ? partial[t] : 0;
    s[t] = orig; __syncthreads();
    for (int off = 1; off < 512; off <<= 1) {
        int u = (t >= off) ? s[t - off] : 0;
        __syncthreads();
        s[t] += u;
        __syncthreads();
    }
    if (t < nb) partial[t] = s[t] - orig;
    if (t == 0) rowp[N_NODES] = N_EDGES;
}

__global__ void scan_final_dinv(const int* __restrict__ cnt, const int* __restrict__ partial,
                                int* __restrict__ rowp, int* __restrict__ cur,
                                float* __restrict__ dinv) {
    __shared__ int s[256];
    int t = threadIdx.x;
    int i = blockIdx.x * 256 + t;
    int v = (i < N_NODES) ? cnt[i] : 0;
    s[t] = v; __syncthreads();
    for (int off = 1; off < 256; off <<= 1) {
        int u = (t >= off) ? s[t - off] : 0;
        __syncthreads();
        s[t] += u;
        __syncthreads();
    }
    if (i < N_NODES) {
        int r = partial[blockIdx.x] + s[t] - v;
        rowp[i] = r;
        cur[i] = r;
        dinv[i] = rsqrtf(1.0f + (float)v);
    }
}

// ---------------- scatter (R8 strided form) + split_x streaming freight ----------------
// Scatter blocks first (long pole, latency-bound); split_x blocks fill issue slack.
__global__ __launch_bounds__(256) void scatter_splitx(
        const int* __restrict__ src, const int* __restrict__ dst,
        const float* __restrict__ dinv, int* __restrict__ cur,
        int2* __restrict__ ep,
        const float* __restrict__ x, u16* __restrict__ x_bf) {
    int bid = blockIdx.x;
    if (bid < CD_BLKS) {
        int base = bid * 1024 + threadIdx.x;
#pragma unroll
        for (int q = 0; q < 4; q++) {
            int e = base + q * 256;
            if (e < N_EDGES) {
                int d = dst[e];
                int s = src[e];
                float w = dinv[d] * dinv[s];
                int pos = atomicAdd(&cur[d], 1);
                int2 v; v.x = s; v.y = __float_as_int(w);
                ep[pos] = v;
            }
        }
        return;
    }
    bid -= CD_BLKS;
    {   // split_x: 4 floats/thread, 12500 blocks
        int idx = bid * 256 + threadIdx.x;
        float4 f = *(const float4*)&x[(size_t)idx * 4];
        ushort4 o;
        o.x = f2bf(f.x); o.y = f2bf(f.y); o.z = f2bf(f.z); o.w = f2bf(f.w);
        *(ushort4*)&x_bf[(size_t)idx * 4] = o;
    }
}

// ---------------- aggregation: half-wave (32 lanes x ushort8) per node, H=256 ----------------
__global__ __launch_bounds__(256) void gcn_agg256(
        const u16* __restrict__ in, const int* __restrict__ rowp,
        const int2* __restrict__ ep, const float* __restrict__ dinv,
        u16* __restrict__ outp) {
    int node = blockIdx.x * 8 + (threadIdx.x >> 5);
    int l = threadIdx.x & 31;
    int beg = rowp[node], end = rowp[node + 1];
    float a[8] = {};
    int e = beg;
    int2 pr[8];
    bool have = (e + 8 <= end);
    if (have) {
#pragma unroll
        for (int q = 0; q < 8; q++) pr[q] = ep[e + q];
    }
    while (have) {
        int2 g8[8];
#pragma unroll
        for (int q = 0; q < 8; q++) g8[q] = pr[q];
        int en = e + 8;
        bool haven = (en + 8 <= end);
        if (haven) {
#pragma unroll
            for (int q = 0; q < 8; q++) pr[q] = ep[en + q];
        }
#pragma unroll
        for (int q = 0; q < 8; q++) {
            u16x8 u = *(const u16x8*)&in[(size_t)g8[q].x * H + l * 8];
            float wt = __int_as_float(g8[q].y);
#pragma unroll
            for (int r = 0; r < 8; r++) a[r] += bf2f(u[r]) * wt;
        }
        e = en; have = haven;
    }
    for (; e < end; e++) {
        int2 pe = ep[e];
        float wt = __int_as_float(pe.y);
        u16x8 u = *(const u16x8*)&in[(size_t)pe.x * H + l * 8];
#pragma unroll
        for (int r = 0; r < 8; r++) a[r] += bf2f(u[r]) * wt;
    }
    float di = dinv[node];
    u16x8 us = *(const u16x8*)&in[(size_t)node * H + l * 8];
    float dd = di * di;
    u16x8 o;
#pragma unroll
    for (int r = 0; r < 8; r++) o[r] = f2bf(a[r] + bf2f(us[r]) * dd);
    *(u16x8*)&outp[(size_t)node * H + l * 8] = o;
}

// ---------------- aggregation: quarter-wave (16 lanes x ushort8) per node, F=128 ----------------
__global__ __launch_bounds__(256) void gcn_agg128(
        const u16* __restrict__ in, const int* __restrict__ rowp,
        const int2* __restrict__ ep, const float* __restrict__ dinv,
        u16* __restrict__ outp) {
    int node = blockIdx.x * 16 + (threadIdx.x >> 4);
    int l = threadIdx.x & 15;
    int beg = rowp[node], end = rowp[node + 1];
    float a[8] = {};
    int e = beg;
    int2 pr[8];
    bool have = (e + 8 <= end);
    if (have) {
#pragma unroll
        for (int q = 0; q < 8; q++) pr[q] = ep[e + q];
    }
    while (have) {
        int2 g8[8];
#pragma unroll
        for (int q = 0; q < 8; q++) g8[q] = pr[q];
        int en = e + 8;
        bool haven = (en + 8 <= end);
        if (haven) {
#pragma unroll
            for (int q = 0; q < 8; q++) pr[q] = ep[en + q];
        }
#pragma unroll
        for (int q = 0; q < 8; q++) {
            u16x8 u = *(const u16x8*)&in[(size_t)g8[q].x * F_IN + l * 8];
            float wt = __int_as_float(g8[q].y);
#pragma unroll
            for (int r = 0; r < 8; r++) a[r] += bf2f(u[r]) * wt;
        }
        e = en; have = haven;
    }
    for (; e < end; e++) {
        int2 pe = ep[e];
        float wt = __int_as_float(pe.y);
        u16x8 u = *(const u16x8*)&in[(size_t)pe.x * F_IN + l * 8];
#pragma unroll
        for (int r = 0; r < 8; r++) a[r] += bf2f(u[r]) * wt;
    }
    float di = dinv[node];
    u16x8 us = *(const u16x8*)&in[(size_t)node * F_IN + l * 8];
    float dd = di * di;
    u16x8 o;
#pragma unroll
    for (int r = 0; r < 8; r++) o[r] = f2bf(a[r] + bf2f(us[r]) * dd);
    *(u16x8*)&outp[(size_t)node * F_IN + l * 8] = o;
}

// ---------------- MFMA GEMM with bias(+relu) epilogue (node layers) ----------------
template<int K, bool RELU>
__global__ __launch_bounds__(256) void gemm_bias(
        const u16* __restrict__ A,
        const u16* __restrict__ Bhi, const u16* __restrict__ Blo,
        const float* __restrict__ bias, u16* __restrict__ C, int M) {
    __shared__ __align__(16) u16 sA[128 * 40];
    __shared__ __align__(16) u16 sB[2 * 128 * 40];
    const int tid = threadIdx.x;
    const int w = tid >> 6, l = tid & 63;
    const int wm = (w & 1) * 64, wn = (w >> 1) * 64;
    const int bm = blockIdx.x * 128, bn = blockIdx.y * 128;
    const int srow = tid >> 2;
    const int schunk = (tid & 3) * 8;
    const int lr = l & 15, lg = (l >> 4) * 8;

    f32x4 acc[4][4] = {};

    for (int k0 = 0; k0 < K; k0 += 32) {
        {
            int r0 = bm + srow, r1 = bm + srow + 64;
            u16x8 v0 = {}, v1 = {};
            if (r0 < M) v0 = *(const u16x8*)&A[(size_t)r0 * K + k0 + schunk];
            if (r1 < M) v1 = *(const u16x8*)&A[(size_t)r1 * K + k0 + schunk];
            *(u16x8*)&sA[srow * 40 + schunk] = v0;
            *(u16x8*)&sA[(srow + 64) * 40 + schunk] = v1;
        }
        {
            int n0 = bn + srow, n1 = bn + srow + 64;
            *(u16x8*)&sB[srow * 40 + schunk] = *(const u16x8*)&Bhi[(size_t)n0 * K + k0 + schunk];
            *(u16x8*)&sB[(srow + 64) * 40 + schunk] = *(const u16x8*)&Bhi[(size_t)n1 * K + k0 + schunk];
            *(u16x8*)&sB[128 * 40 + srow * 40 + schunk] = *(const u16x8*)&Blo[(size_t)n0 * K + k0 + schunk];
            *(u16x8*)&sB[128 * 40 + (srow + 64) * 40 + schunk] = *(const u16x8*)&Blo[(size_t)n1 * K + k0 + schunk];
        }
        __syncthreads();

        s16x8 af[4], bh[4], bl[4];
#pragma unroll
        for (int i = 0; i < 4; i++)
            af[i] = __builtin_bit_cast(s16x8, *(const u16x8*)&sA[(wm + i * 16 + lr) * 40 + lg]);
#pragma unroll
        for (int j = 0; j < 4; j++) {
            bh[j] = __builtin_bit_cast(s16x8, *(const u16x8*)&sB[(wn + j * 16 + lr) * 40 + lg]);
            bl[j] = __builtin_bit_cast(s16x8, *(const u16x8*)&sB[128 * 40 + (wn + j * 16 + lr) * 40 + lg]);
        }
#pragma unroll
        for (int i = 0; i < 4; i++) {
#pragma unroll
            for (int j = 0; j < 4; j++) {
                acc[i][j] = __builtin_amdgcn_mfma_f32_16x16x32_bf16(af[i], bh[j], acc[i][j], 0, 0, 0);
                acc[i][j] = __builtin_amdgcn_mfma_f32_16x16x32_bf16(af[i], bl[j], acc[i][j], 0, 0, 0);
            }
        }
        __syncthreads();
    }

    float bcol[4];
#pragma unroll
    for (int j = 0; j < 4; j++) bcol[j] = bias[bn + wn + j * 16 + lr];

    const int lq = (l >> 4) * 4;
#pragma unroll
    for (int i = 0; i < 4; i++) {
#pragma unroll
        for (int r0 = 0; r0 < 4; r0++) {
            int row = bm + wm + i * 16 + lq + r0;
            if (row < M) {
#pragma unroll
                for (int j = 0; j < 4; j++) {
                    float v = acc[i][j][r0] + bcol[j];
                    if (RELU) v = fmaxf(v, 0.f);
                    C[(size_t)row * H + bn + wn + j * 16 + lr] = f2bf(v);
                }
            }
        }
    }
}

// ---------------- split-precision MFMA GEMM (MLP tail) ----------------
template<int K, int NW, bool RELU, bool F32OUT>
__global__ __launch_bounds__(256) void gemm_split(
        const u16* __restrict__ Ahi, const u16* __restrict__ Alo,
        const u16* __restrict__ Bhi, const u16* __restrict__ Blo,
        const float* __restrict__ bias,
        u16* __restrict__ Chi, u16* __restrict__ Clo, float* __restrict__ Cf,
        int M) {
    __shared__ __align__(16) u16 sA[2 * 128 * 40];
    __shared__ __align__(16) u16 sB[2 * 128 * 40];
    const int tid = threadIdx.x;
    const int w = tid >> 6, l = tid & 63;
    const int wm = (w & 1) * 64, wn = (w >> 1) * 64;
    const int bm = blockIdx.x * 128, bn = blockIdx.y * 128;
    const int srow = tid >> 2;
    const int schunk = (tid & 3) * 8;
    const int lr = l & 15, lg = (l >> 4) * 8;

    f32x4 acc[4][4] = {};

    for (int k0 = 0; k0 < K; k0 += 32) {
        {
            int r0 = bm + srow, r1 = bm + srow + 64;
            u16x8 v0 = {}, v1 = {}, w0 = {}, w1 = {};
            if (r0 < M) {
                v0 = *(const u16x8*)&Ahi[(size_t)r0 * K + k0 + schunk];
                w0 = *(const u16x8*)&Alo[(size_t)r0 * K + k0 + schunk];
            }
            if (r1 < M) {
                v1 = *(const u16x8*)&Ahi[(size_t)r1 * K + k0 + schunk];
                w1 = *(const u16x8*)&Alo[(size_t)r1 * K + k0 + schunk];
            }
            *(u16x8*)&sA[srow * 40 + schunk] = v0;
            *(u16x8*)&sA[(srow + 64) * 40 + schunk] = v1;
            *(u16x8*)&sA[128 * 40 + srow * 40 + schunk] = w0;
            *(u16x8*)&sA[128 * 40 + (srow + 64) * 40 + schunk] = w1;
        }
        {
            int n0 = bn + srow, n1 = bn + srow + 64;
            *(u16x8*)&sB[srow * 40 + schunk] = *(const u16x8*)&Bhi[(size_t)n0 * K + k0 + schunk];
            *(u16x8*)&sB[(srow + 64) * 40 + schunk] = *(const u16x8*)&Bhi[(size_t)n1 * K + k0 + schunk];
            *(u16x8*)&sB[128 * 40 + srow * 40 + schunk] = *(const u16x8*)&Blo[(size_t)n0 * K + k0 + schunk];
            *(u16x8*)&sB[128 * 40 + (srow + 64) * 40 + schunk] = *(const u16x8*)&Blo[(size_t)n1 * K + k0 + schunk];
        }
        __syncthreads();

        s16x8 af[4], al[4], bh[4], bl[4];
#pragma unroll
        for (int i = 0; i < 4; i++) {
            af[i] = __builtin_bit_cast(s16x8, *(const u16x8*)&sA[(wm + i * 16 + lr) * 40 + lg]);
            al[i] = __builtin_bit_cast(s16x8, *(const u16x8*)&sA[128 * 40 + (wm + i * 16 + lr) * 40 + lg]);
        }
#pragma unroll
        for (int j = 0; j < 4; j++) {
            bh[j] = __builtin_bit_cast(s16x8, *(const u16x8*)&sB[(wn + j * 16 + lr) * 40 + lg]);
            bl[j] = __builtin_bit_cast(s16x8, *(const u16x8*)&sB[128 * 40 + (wn + j * 16 + lr) * 40 + lg]);
        }
#pragma unroll
        for (int i = 0; i < 4; i++) {
#pragma unroll
            for (int j = 0; j < 4; j++) {
                acc[i][j] = __builtin_amdgcn_mfma_f32_16x16x32_bf16(af[i], bh[j], acc[i][j], 0, 0, 0);
                acc[i][j] = __builtin_amdgcn_mfma_f32_16x16x32_bf16(af[i], bl[j], acc[i][j], 0, 0, 0);
                acc[i][j] = __builtin_amdgcn_mfma_f32_16x16x32_bf16(al[i], bh[j], acc[i][j], 0, 0, 0);
            }
        }
        __syncthreads();
    }

    float bcol[4];
#pragma unroll
    for (int j = 0; j < 4; j++) bcol[j] = bias[bn + wn + j * 16 + lr];

    const int lq = (l >> 4) * 4;
#pragma unroll
    for (int i = 0; i < 4; i++) {
#pragma unroll
        for (int r0 = 0; r0 < 4; r0++) {
            int row = bm + wm + i * 16 + lq + r0;
            if (row < M) {
#pragma unroll
                for (int j = 0; j < 4; j++) {
                    float v = acc[i][j][r0] + bcol[j];
                    if (RELU) v = fmaxf(v, 0.f);
                    size_t idx = (size_t)row * NW + bn + wn + j * 16 + lr;
                    if (F32OUT) {
                        Cf[idx] = v;
                    } else {
                        u16 hv = f2bf(v);
                        Chi[idx] = hv;
                        Clo[idx] = f2bf(v - bf2f(hv));
                    }
                }
            }
        }
    }
}

// ---------------- pool: per-graph mean of a3, output hi/lo bf16 split ----------------
__global__ __launch_bounds__(256) void pool_split(
        const u16* __restrict__ a3, const int* __restrict__ goff,
        u16* __restrict__ phi, u16* __restrict__ plo) {
    int g = blockIdx.x, t = threadIdx.x;
    int beg = goff[g], end = goff[g + 1];
    float acc = 0.f;
    int i = beg;
    for (; i + 4 <= end; i += 4) {
        float v0 = bf2f(a3[(size_t)(i + 0) * H + t]);
        float v1 = bf2f(a3[(size_t)(i + 1) * H + t]);
        float v2 = bf2f(a3[(size_t)(i + 2) * H + t]);
        float v3 = bf2f(a3[(size_t)(i + 3) * H + t]);
        acc += (v0 + v1) + (v2 + v3);
    }
    for (; i < end; i++) acc += bf2f(a3[(size_t)i * H + t]);
    acc /= fmaxf((float)(end - beg), 1.f);
    u16 hv = f2bf(acc);
    phi[g * H + t] = hv;
    plo[g * H + t] = f2bf(acc - bf2f(hv));
}

// ---------------- launch ----------------
extern "C" void kernel_launch(void* const* d_in, const int* in_sizes, int n_in,
                              void* d_out, int out_size, void* d_ws, size_t ws_size,
                              hipStream_t stream) {
    const float* x   = (const float*)d_in[0];
    const int*   src = (const int*)d_in[1];
    const int*   dst = (const int*)d_in[2];
    const int*   bat = (const int*)d_in[3];
    const float* W1  = (const float*)d_in[4];  const float* b1  = (const float*)d_in[5];
    const float* W2  = (const float*)d_in[6];  const float* b2  = (const float*)d_in[7];
    const float* W3  = (const float*)d_in[8];  const float* b3  = (const float*)d_in[9];
    const float* Wm1 = (const float*)d_in[10]; const float* bm1 = (const float*)d_in[11];
    const float* Wm2 = (const float*)d_in[12]; const float* bm2 = (const float*)d_in[13];
    float* out = (float*)d_out;

    char* p = (char*)d_ws;
    auto carve = [&](size_t bytes) -> void* {
        void* r = (void*)p;
        p += (bytes + 511) & ~(size_t)511;
        return r;
    };
    u16*   x_bf    = (u16*)  carve((size_t)N_NODES * F_IN * 2);
    u16*   aggX    = (u16*)  carve((size_t)N_NODES * F_IN * 2);
    u16*   bufA    = (u16*)  carve((size_t)N_NODES * H * 2);
    u16*   bufB    = (u16*)  carve((size_t)N_NODES * H * 2);
    float* dinv    = (float*)carve((size_t)N_NODES * 4);
    int*   degc    = (int*)  carve((size_t)N_NODES * 4);
    int*   rowp    = (int*)  carve((size_t)(N_NODES + 1) * 4);
    int*   cur     = (int*)  carve((size_t)N_NODES * 4);
    int2*  ep      = (int2*) carve((size_t)N_EDGES * 8);
    int*   partial = (int*)  carve(4096);
    int*   goff    = (int*)  carve((size_t)(G_GR + 1) * 4);
    u16*   Wt1_hi  = (u16*)  carve((size_t)F_IN * H * 2);
    u16*   Wt1_lo  = (u16*)  carve((size_t)F_IN * H * 2);
    u16*   Wt2_hi  = (u16*)  carve((size_t)H * H * 2);
    u16*   Wt2_lo  = (u16*)  carve((size_t)H * H * 2);
    u16*   Wt3_hi  = (u16*)  carve((size_t)H * H * 2);
    u16*   Wt3_lo  = (u16*)  carve((size_t)H * H * 2);
    u16*   Wm1t_hi = (u16*)  carve((size_t)H * NHID * 2);
    u16*   Wm1t_lo = (u16*)  carve((size_t)H * NHID * 2);
    u16*   Wm2t_hi = (u16*)  carve((size_t)NHID * NOUT * 2);
    u16*   Wm2t_lo = (u16*)  carve((size_t)NHID * NOUT * 2);
    u16*   p_hi    = (u16*)  carve((size_t)G_GR * H * 2);
    u16*   p_lo    = (u16*)  carve((size_t)G_GR * H * 2);
    u16*   y_hi    = (u16*)  carve((size_t)G_GR * H * 2);
    u16*   y_lo    = (u16*)  carve((size_t)G_GR * H * 2);
    u16*   hd_hi   = (u16*)  carve((size_t)G_GR * NHID * 2);
    u16*   hd_lo   = (u16*)  carve((size_t)G_GR * NHID * 2);

    const int NB = (N_NODES + 255) / 256;

    hipMemsetAsync(degc, 0, (size_t)N_NODES * 4, stream);
    prep_head<<<HEAD_BLKS, 256, 0, stream>>>(dst, degc,
                                             W1, Wt1_hi, Wt1_lo,
                                             W2, Wt2_hi, Wt2_lo,
                                             W3, Wt3_hi, Wt3_lo,
                                             Wm1, Wm1t_hi, Wm1t_lo,
                                             Wm2, Wm2t_hi, Wm2t_lo, bat, goff);
    scan_partial<<<NB, 256, 0, stream>>>(degc, partial);
    scan_offsets<<<1, 512, 0, stream>>>(partial, NB, rowp);
    scan_final_dinv<<<NB, 256, 0, stream>>>(degc, partial, rowp, cur, dinv);
    // scatter (R8 strided form) + split_x freight (both LDS-free; scatter blocks first)
    scatter_splitx<<<CD_BLKS + SPX_BLKS, 256, 0, stream>>>(src, dst, dinv, cur, ep, x, x_bf);

    dim3 ggrid((N_NODES + 127) / 128, 2);

    // layer 1: aggregate-first (256B rows), then transform+bias+relu
    gcn_agg128<<<N_NODES / 16, 256, 0, stream>>>(x_bf, rowp, ep, dinv, aggX);
    gemm_bias<F_IN, true><<<ggrid, 256, 0, stream>>>(aggX, Wt1_hi, Wt1_lo, b1, bufA, N_NODES);
    // layer 2
    gcn_agg256<<<N_NODES / 8, 256, 0, stream>>>(bufA, rowp, ep, dinv, bufB);
    gemm_bias<H, true><<<ggrid, 256, 0, stream>>>(bufB, Wt2_hi, Wt2_lo, b2, bufA, N_NODES);
    // layer 3: aggregate only; W3+b3 folded into pooled domain
    gcn_agg256<<<N_NODES / 8, 256, 0, stream>>>(bufA, rowp, ep, dinv, bufB);

    // tail: pool -> y=pW3+b3 -> hidden=relu(yWm1+bm1) -> out=hidden Wm2+bm2
    pool_split<<<G_GR, 256, 0, stream>>>(bufB, goff, p_hi, p_lo);
    dim3 g3(2, 2), gm1(2, 4), gm2(2, 2);
    gemm_split<H, H, false, false><<<g3, 256, 0, stream>>>(
        p_hi, p_lo, Wt3_hi, Wt3_lo, b3, y_hi, y_lo, nullptr, G_GR);
    gemm_split<H, NHID, true, false><<<gm1, 256, 0, stream>>>(
        y_hi, y_lo, Wm1t_hi, Wm1t_lo, bm1, hd_hi, hd_lo, nullptr, G_GR);
    gemm_split<NHID, NOUT, false, true><<<gm2, 256, 0, stream>>>(
        hd_hi, hd_lo, Wm2t_hi, Wm2t_lo, bm2, nullptr, nullptr, out, G_GR);
}